// Round 9
// baseline (212.085 us; speedup 1.0000x reference)
//
#include <hip/hip_runtime.h>
#include <math.h>

#define F_DIM 128
#define D_LAT 64
#define H_DIM 128

typedef __attribute__((ext_vector_type(8))) short bf16x8;        // 8 bf16 (4 VGPRs)
typedef __attribute__((ext_vector_type(4))) float f32x4;
typedef __attribute__((ext_vector_type(2))) float f32x2;
typedef __attribute__((ext_vector_type(2))) unsigned long long u64x2;

__device__ __forceinline__ unsigned short f2bf(float f) {
    unsigned int u = __builtin_bit_cast(unsigned int, f);
    return (unsigned short)((u + 0x8000u) >> 16);
}

// gather one 16B chunk per lane into LDS (per-lane global addr, dest = wave base + lane*16)
#define GLDS16(gaddr, laddr)                                                        \
    __builtin_amdgcn_global_load_lds(                                               \
        (const __attribute__((address_space(1))) void*)(gaddr),                     \
        (__attribute__((address_space(3))) void*)(laddr), 16, 0, 0)

// 8 fp8 bytes x 8 fp8 bytes -> elementwise product as 8 fp8 bytes (i64)
__device__ __forceinline__ long prod_fp8(unsigned long long qu, unsigned long long qv) {
    const unsigned int ul = (unsigned int)qu, uh = (unsigned int)(qu >> 32);
    const unsigned int vl = (unsigned int)qv, vh = (unsigned int)(qv >> 32);
    const f32x2 u01 = __builtin_amdgcn_cvt_pk_f32_fp8(ul, false);
    const f32x2 u23 = __builtin_amdgcn_cvt_pk_f32_fp8(ul, true);
    const f32x2 u45 = __builtin_amdgcn_cvt_pk_f32_fp8(uh, false);
    const f32x2 u67 = __builtin_amdgcn_cvt_pk_f32_fp8(uh, true);
    const f32x2 v01 = __builtin_amdgcn_cvt_pk_f32_fp8(vl, false);
    const f32x2 v23 = __builtin_amdgcn_cvt_pk_f32_fp8(vl, true);
    const f32x2 v45 = __builtin_amdgcn_cvt_pk_f32_fp8(vh, false);
    const f32x2 v67 = __builtin_amdgcn_cvt_pk_f32_fp8(vh, true);
    const f32x2 p01 = u01 * v01, p23 = u23 * v23;
    const f32x2 p45 = u45 * v45, p67 = u67 * v67;
    unsigned int r0 = __builtin_amdgcn_cvt_pk_fp8_f32(p01[0], p01[1], 0u, false);
    r0 = __builtin_amdgcn_cvt_pk_fp8_f32(p23[0], p23[1], r0, true);
    unsigned int r1 = __builtin_amdgcn_cvt_pk_fp8_f32(p45[0], p45[1], 0u, false);
    r1 = __builtin_amdgcn_cvt_pk_fp8_f32(p67[0], p67[1], r1, true);
    return (long)(((unsigned long long)r1 << 32) | r0);
}

// ---------------- encoder via MFMA: 16 nodes/wave, z stored fp8 e4m3 ----------------
// mfma 16x16x32 layouts (m89-verified, validated by absmax 0.0 in R2-R7):
//   A: lane l, elem j -> A[l&15][(l>>4)*8 + j]
//   B: lane l, elem j -> B[(l>>4)*8 + j][l&15]
//   D: lane l, reg r  -> D[(l>>4)*4 + r][l&15]
__global__ __launch_bounds__(256) void enc_mfma_kernel(
    const float* __restrict__ x, const float* __restrict__ eps,
    const float* __restrict__ Wmu, const float* __restrict__ bmu,
    const float* __restrict__ Wlv, const float* __restrict__ blv,
    unsigned char* __restrict__ zb, float* __restrict__ accum, int nNodes)
{
    const int lane = threadIdx.x & 63;
    const int li   = lane & 15;
    const int gi   = lane >> 4;

    bf16x8 wf[8][4];
#pragma unroll
    for (int t = 0; t < 4; ++t)
#pragma unroll
        for (int s = 0; s < 4; ++s)
#pragma unroll
            for (int j = 0; j < 8; ++j) {
                const int k = s * 32 + gi * 8 + j;
                wf[t][s][j]     = (short)f2bf(Wmu[k * D_LAT + 16 * t + li]);
                wf[t + 4][s][j] = (short)f2bf(Wlv[k * D_LAT + 16 * t + li]);
            }
    float bmu4[4], blv4[4];
#pragma unroll
    for (int t = 0; t < 4; ++t) {
        bmu4[t] = bmu[16 * t + li];
        blv4[t] = blv[16 * t + li];
    }

    const int wid = (blockIdx.x * blockDim.x + threadIdx.x) >> 6;
    const int nw  = (gridDim.x * blockDim.x) >> 6;
    const int NB  = nNodes >> 4;

    float klacc = 0.f;
    for (int nb = wid; nb < NB; nb += nw) {
        const int nbase = nb << 4;
        const float* __restrict__ xrow = x + (size_t)(nbase + li) * F_DIM;

        bf16x8 af[4];
#pragma unroll
        for (int s = 0; s < 4; ++s) {
            const f32x4 v0 = *(const f32x4*)(xrow + s * 32 + gi * 8);
            const f32x4 v1 = *(const f32x4*)(xrow + s * 32 + gi * 8 + 4);
#pragma unroll
            for (int j = 0; j < 4; ++j) {
                af[s][j]     = (short)f2bf(v0[j]);
                af[s][j + 4] = (short)f2bf(v1[j]);
            }
        }

        f32x4 acc[8];
#pragma unroll
        for (int t = 0; t < 4; ++t) {
            acc[t]     = (f32x4){bmu4[t], bmu4[t], bmu4[t], bmu4[t]};
            acc[t + 4] = (f32x4){blv4[t], blv4[t], blv4[t], blv4[t]};
        }
#pragma unroll
        for (int t = 0; t < 8; ++t)
#pragma unroll
            for (int s = 0; s < 4; ++s)
                acc[t] = __builtin_amdgcn_mfma_f32_16x16x32_bf16(af[s], wf[t][s], acc[t], 0, 0, 0);

#pragma unroll
        for (int r = 0; r < 4; ++r) {
            const int row = nbase + gi * 4 + r;
#pragma unroll
            for (int t = 0; t < 4; ++t) {
                const float mu  = acc[t][r];
                const float lv  = acc[t + 4][r];
                const float e05 = __expf(0.5f * lv);
                klacc += mu * mu + e05 * e05 - 1.0f - lv;
                const float zv = fmaf(eps[(size_t)row * D_LAT + 16 * t + li], e05, mu);
                zb[(size_t)row * D_LAT + 16 * t + li] =
                    (unsigned char)(__builtin_amdgcn_cvt_pk_fp8_f32(zv, 0.f, 0u, false) & 0xffu);
            }
        }
    }
    for (int off = 32; off; off >>= 1) klacc += __shfl_xor(klacc, off);
    if (lane == 0) atomicAdd(&accum[1], 0.5f * klacc);
}

// ---------------- edge scorer: LDS gather ring (2 slots/wave), counted vmcnt ----------------
// Per steady-state iteration the wave issues exactly 8 vm-ops (4 idx + 4 glds);
// slot s was staged 2 iterations ago, so s_waitcnt vmcnt(8) at the top of the
// iteration guarantees its data landed without draining the in-flight refill.
__global__ __launch_bounds__(256) void edge_mfma_kernel(
    const unsigned char* __restrict__ zb,
    const int* __restrict__ eidx, const int* __restrict__ nidx,
    const float* __restrict__ W1, const float* __restrict__ b1,
    const float* __restrict__ W2, const float* __restrict__ b2,
    float* __restrict__ accum, int E)
{
    __shared__ unsigned char sh[4][2][4][1024];   // [wave][slot][row-set][64 lanes * 16B]

    const int lane = threadIdx.x & 63;
    const int li   = lane & 15;
    const int gi   = lane >> 4;
    const int w    = threadIdx.x >> 6;

    // W1 quantized to fp8 in registers (permuted-k mapping, consistent A/B): 32 VGPR
    long w1q[8][2];
#pragma unroll
    for (int t = 0; t < 8; ++t)
#pragma unroll
        for (int s = 0; s < 2; ++s) {
            float f[8];
#pragma unroll
            for (int j = 0; j < 8; ++j)
                f[j] = W1[(gi * 16 + s * 8 + j) * H_DIM + 16 * t + li];
            unsigned int r0 = __builtin_amdgcn_cvt_pk_fp8_f32(f[0], f[1], 0u, false);
            r0 = __builtin_amdgcn_cvt_pk_fp8_f32(f[2], f[3], r0, true);
            unsigned int r1 = __builtin_amdgcn_cvt_pk_fp8_f32(f[4], f[5], 0u, false);
            r1 = __builtin_amdgcn_cvt_pk_fp8_f32(f[6], f[7], r1, true);
            w1q[t][s] = (long)(((unsigned long long)r1 << 32) | r0);
        }
    float b1r[8], w2r[8];
#pragma unroll
    for (int t = 0; t < 8; ++t) {
        b1r[t] = b1[16 * t + li];
        w2r[t] = W2[16 * t + li];
    }
    const float b2v = b2[0];

    const int wid = (blockIdx.x * blockDim.x + threadIdx.x) >> 6;
    const int nw  = (gridDim.x * blockDim.x) >> 6;
    const int NBpos = E >> 4;        // 62500 positive blocks
    const int NBH   = NBpos;         // iterations of 2 blocks (2*NBpos blocks total)

    float lp = 0.f;

    auto load_idx = [&](int hb, int& u0, int& v0, int& u1, int& v1) {
        const int h   = (hb < NBH) ? hb : (NBH - 1);
        const int pb0 = 2 * h, pb1 = 2 * h + 1;
        const int* __restrict__ i0 = (pb0 < NBpos) ? eidx : nidx;
        const int* __restrict__ i1 = (pb1 < NBpos) ? eidx : nidx;
        const int m0 = ((pb0 < NBpos) ? pb0 : pb0 - NBpos) << 4;
        const int m1 = ((pb1 < NBpos) ? pb1 : pb1 - NBpos) << 4;
        u0 = i0[m0 + li]; v0 = i0[E + m0 + li];
        u1 = i1[m1 + li]; v1 = i1[E + m1 + li];
    };
    auto stage = [&](int slot, int u0, int v0, int u1, int v1) {
        GLDS16(zb + (size_t)u0 * D_LAT + (gi << 4), &sh[w][slot][0][0]);
        GLDS16(zb + (size_t)v0 * D_LAT + (gi << 4), &sh[w][slot][1][0]);
        GLDS16(zb + (size_t)u1 * D_LAT + (gi << 4), &sh[w][slot][2][0]);
        GLDS16(zb + (size_t)v1 * D_LAT + (gi << 4), &sh[w][slot][3][0]);
    };
    auto do_block = [&](u64x2 qu, u64x2 qv, bool pos) {
        const long pa0 = prod_fp8(qu[0], qv[0]);
        const long pa1 = prod_fp8(qu[1], qv[1]);
        f32x4 acc[8];
#pragma unroll
        for (int t = 0; t < 8; ++t)
            acc[t] = (f32x4){b1r[t], b1r[t], b1r[t], b1r[t]};
#pragma unroll
        for (int t = 0; t < 8; ++t) {
            acc[t] = __builtin_amdgcn_mfma_f32_16x16x32_fp8_fp8(pa0, w1q[t][0], acc[t], 0, 0, 0);
            acc[t] = __builtin_amdgcn_mfma_f32_16x16x32_fp8_fp8(pa1, w1q[t][1], acc[t], 0, 0, 0);
        }
        float t0 = 0.f, t1 = 0.f, t2 = 0.f, t3 = 0.f;
#pragma unroll
        for (int t = 0; t < 8; ++t) {
            t0 += fmaxf(acc[t][0], 0.f) * w2r[t];
            t1 += fmaxf(acc[t][1], 0.f) * w2r[t];
            t2 += fmaxf(acc[t][2], 0.f) * w2r[t];
            t3 += fmaxf(acc[t][3], 0.f) * w2r[t];
        }
#pragma unroll
        for (int off = 1; off < 16; off <<= 1) {
            t0 += __shfl_xor(t0, off);
            t1 += __shfl_xor(t1, off);
            t2 += __shfl_xor(t2, off);
            t3 += __shfl_xor(t3, off);
        }
        const float sg = pos ? 1.f : -1.f;
        const float l0 = sg * (t0 + b2v), l1 = sg * (t1 + b2v);
        const float l2 = sg * (t2 + b2v), l3 = sg * (t3 + b2v);
        lp += fminf(l0, 0.f) - __logf(1.f + __expf(-fabsf(l0)));
        lp += fminf(l1, 0.f) - __logf(1.f + __expf(-fabsf(l1)));
        lp += fminf(l2, 0.f) - __logf(1.f + __expf(-fabsf(l2)));
        lp += fminf(l3, 0.f) - __logf(1.f + __expf(-fabsf(l3)));
    };

    // ---- prologue: fill both slots (data for iters wid, wid+nw), idx for wid+2nw ----
    int iu0, iv0, iu1, iv1;
    load_idx(wid, iu0, iv0, iu1, iv1);
    stage(0, iu0, iv0, iu1, iv1);
    load_idx(wid + nw, iu0, iv0, iu1, iv1);
    stage(1, iu0, iv0, iu1, iv1);
    load_idx(wid + 2 * nw, iu0, iv0, iu1, iv1);

    int slot = 0;
    for (int hb = wid; hb < NBH; hb += nw, slot ^= 1) {
        // slot's stage is 2 iterations old; everything issued since is <= 8 vm-ops
        asm volatile("s_waitcnt vmcnt(8)" ::: "memory");
        const unsigned char* base = &sh[w][slot][0][0];
        const u64x2 qu0 = *(const u64x2*)(base + (lane << 4));
        const u64x2 qv0 = *(const u64x2*)(base + 1024 + (lane << 4));
        const u64x2 qu1 = *(const u64x2*)(base + 2048 + (lane << 4));
        const u64x2 qv1 = *(const u64x2*)(base + 3072 + (lane << 4));
        // reads must land in VGPRs before this slot is re-staged (WAR on LDS)
        asm volatile("s_waitcnt lgkmcnt(0)" ::: "memory");

        int ju0, jv0, ju1, jv1;
        load_idx(hb + 3 * nw, ju0, jv0, ju1, jv1);   // idx for iter hb+3nw (4 vm-ops)
        stage(slot, iu0, iv0, iu1, iv1);             // refill slot for iter hb+2nw (4 vm-ops)
        iu0 = ju0; iv0 = jv0; iu1 = ju1; iv1 = jv1;

        do_block(qu0, qv0, 2 * hb < NBpos);
        do_block(qu1, qv1, 2 * hb + 1 < NBpos);
    }

    for (int off = 32; off; off >>= 1) lp += __shfl_xor(lp, off);
    if (lane == 0) atomicAdd(&accum[0], lp * 0.0625f);
}

// ---------------- finalize ----------------
__global__ void fin_kernel(const float* __restrict__ accum, float* __restrict__ out,
                           int nNodes, int E)
{
    const float recon = accum[0] / (float)(2 * E);
    const float kl    = accum[1] / (float)nNodes;
    out[0] = kl - recon;
}

extern "C" void kernel_launch(void* const* d_in, const int* in_sizes, int n_in,
                              void* d_out, int out_size, void* d_ws, size_t ws_size,
                              hipStream_t stream)
{
    const float* x    = (const float*)d_in[0];
    const float* eps  = (const float*)d_in[1];
    const float* Wmu  = (const float*)d_in[2];
    const float* bmu  = (const float*)d_in[3];
    const float* Wlv  = (const float*)d_in[4];
    const float* blv  = (const float*)d_in[5];
    const float* W1   = (const float*)d_in[6];
    const float* b1   = (const float*)d_in[7];
    const float* W2   = (const float*)d_in[8];
    const float* b2   = (const float*)d_in[9];
    const int*   eidx = (const int*)d_in[10];
    const int*   nidx = (const int*)d_in[11];

    const int nNodes = in_sizes[1] / D_LAT;   // 100000
    const int E      = in_sizes[10] / 2;      // 1000000

    float* accum      = (float*)d_ws;
    unsigned char* zb = (unsigned char*)((char*)d_ws + 256);   // nNodes*64 fp8 bytes

    hipMemsetAsync(d_ws, 0, 256, stream);
    enc_mfma_kernel<<<512, 256, 0, stream>>>(x, eps, Wmu, bmu, Wlv, blv, zb, accum, nNodes);
    edge_mfma_kernel<<<2048, 256, 0, stream>>>(zb, eidx, nidx, W1, b1, W2, b2, accum, E);
    fin_kernel<<<1, 1, 0, stream>>>(accum, (float*)d_out, nNodes, E);
}

// Round 10
// 179.385 us; speedup vs baseline: 1.1823x; 1.1823x over previous
//
#include <hip/hip_runtime.h>
#include <math.h>

#define F_DIM 128
#define D_LAT 64
#define H_DIM 128

typedef __attribute__((ext_vector_type(8))) short bf16x8;        // 8 bf16 (4 VGPRs)
typedef __attribute__((ext_vector_type(4))) float f32x4;
typedef __attribute__((ext_vector_type(2))) float f32x2;
typedef __attribute__((ext_vector_type(2))) unsigned long long u64x2;

__device__ __forceinline__ unsigned short f2bf(float f) {
    unsigned int u = __builtin_bit_cast(unsigned int, f);
    return (unsigned short)((u + 0x8000u) >> 16);
}

// gather one 16B chunk per lane into LDS (per-lane global addr, dest = wave base + lane*16)
#define GLDS16(gaddr, laddr)                                                        \
    __builtin_amdgcn_global_load_lds(                                               \
        (const __attribute__((address_space(1))) void*)(gaddr),                     \
        (__attribute__((address_space(3))) void*)(laddr), 16, 0, 0)

// 8 fp8 bytes x 8 fp8 bytes -> elementwise product as 8 fp8 bytes (i64)
__device__ __forceinline__ long prod_fp8(unsigned long long qu, unsigned long long qv) {
    const unsigned int ul = (unsigned int)qu, uh = (unsigned int)(qu >> 32);
    const unsigned int vl = (unsigned int)qv, vh = (unsigned int)(qv >> 32);
    const f32x2 u01 = __builtin_amdgcn_cvt_pk_f32_fp8(ul, false);
    const f32x2 u23 = __builtin_amdgcn_cvt_pk_f32_fp8(ul, true);
    const f32x2 u45 = __builtin_amdgcn_cvt_pk_f32_fp8(uh, false);
    const f32x2 u67 = __builtin_amdgcn_cvt_pk_f32_fp8(uh, true);
    const f32x2 v01 = __builtin_amdgcn_cvt_pk_f32_fp8(vl, false);
    const f32x2 v23 = __builtin_amdgcn_cvt_pk_f32_fp8(vl, true);
    const f32x2 v45 = __builtin_amdgcn_cvt_pk_f32_fp8(vh, false);
    const f32x2 v67 = __builtin_amdgcn_cvt_pk_f32_fp8(vh, true);
    const f32x2 p01 = u01 * v01, p23 = u23 * v23;
    const f32x2 p45 = u45 * v45, p67 = u67 * v67;
    unsigned int r0 = __builtin_amdgcn_cvt_pk_fp8_f32(p01[0], p01[1], 0u, false);
    r0 = __builtin_amdgcn_cvt_pk_fp8_f32(p23[0], p23[1], r0, true);
    unsigned int r1 = __builtin_amdgcn_cvt_pk_fp8_f32(p45[0], p45[1], 0u, false);
    r1 = __builtin_amdgcn_cvt_pk_fp8_f32(p67[0], p67[1], r1, true);
    return (long)(((unsigned long long)r1 << 32) | r0);
}

// ---------------- encoder via MFMA: 16 nodes/wave, z stored fp8 e4m3 ----------------
// mfma 16x16x32 layouts (m89-verified, validated by absmax 0.0 in R2-R9):
//   A: lane l, elem j -> A[l&15][(l>>4)*8 + j]
//   B: lane l, elem j -> B[(l>>4)*8 + j][l&15]
//   D: lane l, reg r  -> D[(l>>4)*4 + r][l&15]
__global__ __launch_bounds__(256) void enc_mfma_kernel(
    const float* __restrict__ x, const float* __restrict__ eps,
    const float* __restrict__ Wmu, const float* __restrict__ bmu,
    const float* __restrict__ Wlv, const float* __restrict__ blv,
    unsigned char* __restrict__ zb, float* __restrict__ accum, int nNodes)
{
    const int lane = threadIdx.x & 63;
    const int li   = lane & 15;
    const int gi   = lane >> 4;

    bf16x8 wf[8][4];
#pragma unroll
    for (int t = 0; t < 4; ++t)
#pragma unroll
        for (int s = 0; s < 4; ++s)
#pragma unroll
            for (int j = 0; j < 8; ++j) {
                const int k = s * 32 + gi * 8 + j;
                wf[t][s][j]     = (short)f2bf(Wmu[k * D_LAT + 16 * t + li]);
                wf[t + 4][s][j] = (short)f2bf(Wlv[k * D_LAT + 16 * t + li]);
            }
    float bmu4[4], blv4[4];
#pragma unroll
    for (int t = 0; t < 4; ++t) {
        bmu4[t] = bmu[16 * t + li];
        blv4[t] = blv[16 * t + li];
    }

    const int wid = (blockIdx.x * blockDim.x + threadIdx.x) >> 6;
    const int nw  = (gridDim.x * blockDim.x) >> 6;
    const int NB  = nNodes >> 4;

    float klacc = 0.f;
    for (int nb = wid; nb < NB; nb += nw) {
        const int nbase = nb << 4;
        const float* __restrict__ xrow = x + (size_t)(nbase + li) * F_DIM;

        bf16x8 af[4];
#pragma unroll
        for (int s = 0; s < 4; ++s) {
            const f32x4 v0 = *(const f32x4*)(xrow + s * 32 + gi * 8);
            const f32x4 v1 = *(const f32x4*)(xrow + s * 32 + gi * 8 + 4);
#pragma unroll
            for (int j = 0; j < 4; ++j) {
                af[s][j]     = (short)f2bf(v0[j]);
                af[s][j + 4] = (short)f2bf(v1[j]);
            }
        }

        f32x4 acc[8];
#pragma unroll
        for (int t = 0; t < 4; ++t) {
            acc[t]     = (f32x4){bmu4[t], bmu4[t], bmu4[t], bmu4[t]};
            acc[t + 4] = (f32x4){blv4[t], blv4[t], blv4[t], blv4[t]};
        }
#pragma unroll
        for (int t = 0; t < 8; ++t)
#pragma unroll
            for (int s = 0; s < 4; ++s)
                acc[t] = __builtin_amdgcn_mfma_f32_16x16x32_bf16(af[s], wf[t][s], acc[t], 0, 0, 0);

#pragma unroll
        for (int r = 0; r < 4; ++r) {
            const int row = nbase + gi * 4 + r;
#pragma unroll
            for (int t = 0; t < 4; ++t) {
                const float mu  = acc[t][r];
                const float lv  = acc[t + 4][r];
                const float e05 = __expf(0.5f * lv);
                klacc += mu * mu + e05 * e05 - 1.0f - lv;
                const float zv = fmaf(eps[(size_t)row * D_LAT + 16 * t + li], e05, mu);
                zb[(size_t)row * D_LAT + 16 * t + li] =
                    (unsigned char)(__builtin_amdgcn_cvt_pk_fp8_f32(zv, 0.f, 0u, false) & 0xffu);
            }
        }
    }
    for (int off = 32; off; off >>= 1) klacc += __shfl_xor(klacc, off);
    if (lane == 0) atomicAdd(&accum[1], 0.5f * klacc);
}

// ---------------- edge scorer: 512-thr blocks (8 waves), LDS ring, counted vmcnt ----------------
// Residency: 64KB static LDS/block, 2 blocks/CU -> 16 waves/CU guaranteed (vs ~6-8 measured
// with 256-thr blocks in R3-R9). Per steady-state iteration each wave issues exactly 8 vm-ops
// (4 idx + 4 glds); slot s was staged 2 iterations ago -> s_waitcnt vmcnt(8) at iteration top.
__global__ __launch_bounds__(512) void edge_mfma_kernel(
    const unsigned char* __restrict__ zb,
    const int* __restrict__ eidx, const int* __restrict__ nidx,
    const float* __restrict__ W1, const float* __restrict__ b1,
    const float* __restrict__ W2, const float* __restrict__ b2,
    float* __restrict__ accum, int E)
{
    __shared__ unsigned char sh[8][2][4][1024];   // [wave][slot][row-set][64 lanes * 16B] = 64KB

    const int lane = threadIdx.x & 63;
    const int li   = lane & 15;
    const int gi   = lane >> 4;
    const int w    = threadIdx.x >> 6;

    // W1 quantized to fp8 in registers (permuted-k mapping, consistent A/B): 32 VGPR
    long w1q[8][2];
#pragma unroll
    for (int t = 0; t < 8; ++t)
#pragma unroll
        for (int s = 0; s < 2; ++s) {
            float f[8];
#pragma unroll
            for (int j = 0; j < 8; ++j)
                f[j] = W1[(gi * 16 + s * 8 + j) * H_DIM + 16 * t + li];
            unsigned int r0 = __builtin_amdgcn_cvt_pk_fp8_f32(f[0], f[1], 0u, false);
            r0 = __builtin_amdgcn_cvt_pk_fp8_f32(f[2], f[3], r0, true);
            unsigned int r1 = __builtin_amdgcn_cvt_pk_fp8_f32(f[4], f[5], 0u, false);
            r1 = __builtin_amdgcn_cvt_pk_fp8_f32(f[6], f[7], r1, true);
            w1q[t][s] = (long)(((unsigned long long)r1 << 32) | r0);
        }
    float b1r[8], w2r[8];
#pragma unroll
    for (int t = 0; t < 8; ++t) {
        b1r[t] = b1[16 * t + li];
        w2r[t] = W2[16 * t + li];
    }
    const float b2v = b2[0];

    const int wid = (blockIdx.x * blockDim.x + threadIdx.x) >> 6;
    const int nw  = (gridDim.x * blockDim.x) >> 6;
    const int NBpos = E >> 4;        // 62500 positive blocks
    const int NBH   = NBpos;         // iterations of 2 blocks (2*NBpos blocks total)

    float lp = 0.f;

    auto load_idx = [&](int hb, int& u0, int& v0, int& u1, int& v1) {
        const int h   = (hb < NBH) ? hb : (NBH - 1);
        const int pb0 = 2 * h, pb1 = 2 * h + 1;
        const int* __restrict__ i0 = (pb0 < NBpos) ? eidx : nidx;
        const int* __restrict__ i1 = (pb1 < NBpos) ? eidx : nidx;
        const int m0 = ((pb0 < NBpos) ? pb0 : pb0 - NBpos) << 4;
        const int m1 = ((pb1 < NBpos) ? pb1 : pb1 - NBpos) << 4;
        u0 = i0[m0 + li]; v0 = i0[E + m0 + li];
        u1 = i1[m1 + li]; v1 = i1[E + m1 + li];
    };
    auto stage = [&](int slot, int u0, int v0, int u1, int v1) {
        GLDS16(zb + (size_t)u0 * D_LAT + (gi << 4), &sh[w][slot][0][0]);
        GLDS16(zb + (size_t)v0 * D_LAT + (gi << 4), &sh[w][slot][1][0]);
        GLDS16(zb + (size_t)u1 * D_LAT + (gi << 4), &sh[w][slot][2][0]);
        GLDS16(zb + (size_t)v1 * D_LAT + (gi << 4), &sh[w][slot][3][0]);
    };
    auto do_block = [&](u64x2 qu, u64x2 qv, bool pos) {
        const long pa0 = prod_fp8(qu[0], qv[0]);
        const long pa1 = prod_fp8(qu[1], qv[1]);
        f32x4 acc[8];
#pragma unroll
        for (int t = 0; t < 8; ++t)
            acc[t] = (f32x4){b1r[t], b1r[t], b1r[t], b1r[t]};
#pragma unroll
        for (int t = 0; t < 8; ++t) {
            acc[t] = __builtin_amdgcn_mfma_f32_16x16x32_fp8_fp8(pa0, w1q[t][0], acc[t], 0, 0, 0);
            acc[t] = __builtin_amdgcn_mfma_f32_16x16x32_fp8_fp8(pa1, w1q[t][1], acc[t], 0, 0, 0);
        }
        float t0 = 0.f, t1 = 0.f, t2 = 0.f, t3 = 0.f;
#pragma unroll
        for (int t = 0; t < 8; ++t) {
            t0 += fmaxf(acc[t][0], 0.f) * w2r[t];
            t1 += fmaxf(acc[t][1], 0.f) * w2r[t];
            t2 += fmaxf(acc[t][2], 0.f) * w2r[t];
            t3 += fmaxf(acc[t][3], 0.f) * w2r[t];
        }
#pragma unroll
        for (int off = 1; off < 16; off <<= 1) {
            t0 += __shfl_xor(t0, off);
            t1 += __shfl_xor(t1, off);
            t2 += __shfl_xor(t2, off);
            t3 += __shfl_xor(t3, off);
        }
        const float sg = pos ? 1.f : -1.f;
        const float l0 = sg * (t0 + b2v), l1 = sg * (t1 + b2v);
        const float l2 = sg * (t2 + b2v), l3 = sg * (t3 + b2v);
        lp += fminf(l0, 0.f) - __logf(1.f + __expf(-fabsf(l0)));
        lp += fminf(l1, 0.f) - __logf(1.f + __expf(-fabsf(l1)));
        lp += fminf(l2, 0.f) - __logf(1.f + __expf(-fabsf(l2)));
        lp += fminf(l3, 0.f) - __logf(1.f + __expf(-fabsf(l3)));
    };

    // ---- prologue: fill both slots (data for iters wid, wid+nw), idx for wid+2nw ----
    int iu0, iv0, iu1, iv1;
    load_idx(wid, iu0, iv0, iu1, iv1);
    stage(0, iu0, iv0, iu1, iv1);
    load_idx(wid + nw, iu0, iv0, iu1, iv1);
    stage(1, iu0, iv0, iu1, iv1);
    load_idx(wid + 2 * nw, iu0, iv0, iu1, iv1);

    int slot = 0;
    for (int hb = wid; hb < NBH; hb += nw, slot ^= 1) {
        // slot's stage is 2 iterations old; everything issued since is <= 8 vm-ops
        asm volatile("s_waitcnt vmcnt(8)" ::: "memory");
        const unsigned char* base = &sh[w][slot][0][0];
        const u64x2 qu0 = *(const u64x2*)(base + (lane << 4));
        const u64x2 qv0 = *(const u64x2*)(base + 1024 + (lane << 4));
        const u64x2 qu1 = *(const u64x2*)(base + 2048 + (lane << 4));
        const u64x2 qv1 = *(const u64x2*)(base + 3072 + (lane << 4));
        // reads must land in VGPRs before this slot is re-staged (WAR on LDS)
        asm volatile("s_waitcnt lgkmcnt(0)" ::: "memory");

        int ju0, jv0, ju1, jv1;
        load_idx(hb + 3 * nw, ju0, jv0, ju1, jv1);   // idx for iter hb+3nw (4 vm-ops)
        stage(slot, iu0, iv0, iu1, iv1);             // refill slot for iter hb+2nw (4 vm-ops)
        iu0 = ju0; iv0 = jv0; iu1 = ju1; iv1 = jv1;

        do_block(qu0, qv0, 2 * hb < NBpos);
        do_block(qu1, qv1, 2 * hb + 1 < NBpos);
    }

    for (int off = 32; off; off >>= 1) lp += __shfl_xor(lp, off);
    if (lane == 0) atomicAdd(&accum[0], lp * 0.0625f);
}

// ---------------- finalize ----------------
__global__ void fin_kernel(const float* __restrict__ accum, float* __restrict__ out,
                           int nNodes, int E)
{
    const float recon = accum[0] / (float)(2 * E);
    const float kl    = accum[1] / (float)nNodes;
    out[0] = kl - recon;
}

extern "C" void kernel_launch(void* const* d_in, const int* in_sizes, int n_in,
                              void* d_out, int out_size, void* d_ws, size_t ws_size,
                              hipStream_t stream)
{
    const float* x    = (const float*)d_in[0];
    const float* eps  = (const float*)d_in[1];
    const float* Wmu  = (const float*)d_in[2];
    const float* bmu  = (const float*)d_in[3];
    const float* Wlv  = (const float*)d_in[4];
    const float* blv  = (const float*)d_in[5];
    const float* W1   = (const float*)d_in[6];
    const float* b1   = (const float*)d_in[7];
    const float* W2   = (const float*)d_in[8];
    const float* b2   = (const float*)d_in[9];
    const int*   eidx = (const int*)d_in[10];
    const int*   nidx = (const int*)d_in[11];

    const int nNodes = in_sizes[1] / D_LAT;   // 100000
    const int E      = in_sizes[10] / 2;      // 1000000

    float* accum      = (float*)d_ws;
    unsigned char* zb = (unsigned char*)((char*)d_ws + 256);   // nNodes*64 fp8 bytes

    hipMemsetAsync(d_ws, 0, 256, stream);
    enc_mfma_kernel<<<512, 256, 0, stream>>>(x, eps, Wmu, bmu, Wlv, blv, zb, accum, nNodes);
    edge_mfma_kernel<<<512, 512, 0, stream>>>(zb, eidx, nidx, W1, b1, W2, b2, accum, E);
    fin_kernel<<<1, 1, 0, stream>>>(accum, (float*)d_out, nNodes, E);
}